// Round 17
// baseline (60.370 us; speedup 1.0000x reference)
//
#include <hip/hip_runtime.h>
#include <math.h>

#define T_ 12
#define CIN_ 16
#define CE_ 8
#define HID_ 32
#define MAXD 32   // slots/node; in-degree ~ Poisson(10), P(deg>32) ~ 1e-8/node

typedef __attribute__((ext_vector_type(8))) short short8;
typedef __attribute__((ext_vector_type(4))) float f32x4;

__device__ __forceinline__ int rli(int v, int l) { return __builtin_amdgcn_readlane(v, l); }
__device__ __forceinline__ float rlf(float v, int l) {
    return __int_as_float(__builtin_amdgcn_readlane(__float_as_int(v), l));
}
__device__ __forceinline__ unsigned short f2bf(float f) {
    unsigned u = __float_as_uint(f);
    return (unsigned short)((u + 0x7fffu + ((u >> 16) & 1u)) >> 16);   // RNE
}
__device__ __forceinline__ float bf2f(unsigned short s) { return __uint_as_float((unsigned)s << 16); }
__device__ __forceinline__ float bflo(unsigned u) { return __uint_as_float(u << 16); }
__device__ __forceinline__ float bfhi(unsigned u) { return __uint_as_float(u & 0xffff0000u); }

__device__ __forceinline__ float gatef(float r, float u) {
    float S  = __builtin_amdgcn_rcpf(1.f + __expf(r));                    // 1 - sigmoid(r)
    float HC = 1.f - 2.f * __builtin_amdgcn_rcpf(__expf(2.f * u) + 1.f); // tanh(u), inf-safe
    return S * HC;
}

// ---- transpose x (zeroes cnt) + weight prep on blocks 0,1 ------------------
// B-frag: lane holds B[k=(lane>>4)*8+j][col=b*16+(lane&15)], j=0..7.
// Layer 1 weight rows permuted: h stores channel c at position q=2*(c%16)+(c/16),
// so actual_k(q) = (q>>1) | ((q&1)<<4).

__global__ void k_txp(const float* __restrict__ x, unsigned short* __restrict__ Xt,
                      int* __restrict__ cnt, int N,
                      const float* __restrict__ Wg0, const float* __restrict__ Wu0,
                      const float* __restrict__ bg0, const float* __restrict__ bu0,
                      const float* __restrict__ Weg0, const float* __restrict__ Weu0,
                      const float* __restrict__ Wg1, const float* __restrict__ Wu1,
                      const float* __restrict__ bg1, const float* __restrict__ bu1,
                      const float* __restrict__ Weg1, const float* __restrict__ Weu1,
                      short8* __restrict__ BHi, short8* __restrict__ BLo,
                      float* __restrict__ WeD, float* __restrict__ biasD) {
    int id = blockIdx.x * blockDim.x + threadIdx.x;
    if (id < N) cnt[id] = 0;
    int total = N * T_ * 4;
    if (id < total) {
        int n = id / (T_ * 4);
        int r = id - n * (T_ * 4);
        int t = r >> 2, c4 = r & 3;
        float4 v = ((const float4*)x)[((size_t)t * N + n) * 4 + c4];
        ushort4 o;
        o.x = f2bf(v.x); o.y = f2bf(v.y); o.z = f2bf(v.z); o.w = f2bf(v.w);
        *((ushort4*)(Xt + (size_t)n * (T_ * CIN_) + t * CIN_ + c4 * 4)) = o;
    }
    // ---- weight prep on blocks 0,1 (L = blockIdx.x) ----
    if (blockIdx.x >= 2) return;
    int L = blockIdx.x;
    int tid = threadIdx.x;
    int b = tid >> 6, lane = tid & 63;
    int cl = lane & 15;
    int c = b * 16 + cl;                       // cat channel (R half | update half)
    const float* Wg  = L ? Wg1 : Wg0;
    const float* Wu  = L ? Wu1 : Wu0;
    const float* bgp = L ? bg1 : bg0;
    const float* bup = L ? bu1 : bu0;
    const float* Weg = L ? Weg1 : Weg0;
    const float* Weu = L ? Weu1 : Weu0;
    const float* wcol; int wstr;
    if (c < 32) { wcol = Wg + 32 + c; wstr = 64; }     // gate R half: Wg[:,32+c]
    else        { wcol = Wu + (c - 32); wstr = 32; }   // update: Wu[:,c-32]
    int k0 = (lane >> 4) * 8;
    short8 hi8, lo8;
#pragma unroll
    for (int j = 0; j < 8; j++) {
        int kp = k0 + j;
        int ak; bool v;
        if (L) { ak = (kp >> 1) | ((kp & 1) << 4); v = true; }   // de-interleave perm
        else   { ak = kp; v = (kp < CIN_); }                     // K=16, pad zero
        float w = v ? wcol[(size_t)ak * wstr] : 0.f;
        unsigned short hh = f2bf(w);
        unsigned short ll = f2bf(w - bf2f(hh));
        hi8[j] = (short)hh; lo8[j] = (short)ll;
    }
    int idx = (L * 4 + b) * 64 + lane;
    BHi[idx] = hi8;
    BLo[idx] = lo8;
#pragma unroll
    for (int j = 0; j < CE_; j++)
        WeD[(size_t)idx * 8 + j] = (c < 32) ? Weg[j * 64 + 32 + c] : Weu[j * 32 + (c - 32)];
    biasD[idx] = (c < 32) ? bgp[32 + c] : bup[c - 32];
}

// ---- bucket build ----------------------------------------------------------

__global__ void k_build(const int* __restrict__ src, const int* __restrict__ dst, int E,
                        int* __restrict__ cnt, int2* __restrict__ bucket) {
    int e = blockIdx.x * blockDim.x + threadIdx.x;
    if (e >= E) return;
    int s = src[e], d = dst[e];
    int pos = atomicAdd(&cnt[d], 1);
    if (pos < MAXD) bucket[(size_t)d * MAXD + pos] = make_int2(s, e);
}

// ---- fused layer: TWO nodes per wave (A=2gw, B=2gw+1) ----------------------
// Metadata: lanes 0-31 = node A slots, 32-63 = node B slots (one coalesced read
// covers both). Constants (B-frags, WeD, biasD) loaded once per pair. Gathers
// interleaved (8 loads in flight). MFMA runs twice reusing B-fragments.
// A-frag: lane holds feat_row[t=(lane&15)][k=(lane>>4)*8+j] (t>=12 discarded).

template<int L0>
__global__ __launch_bounds__(256, 4)
void k_layer(const unsigned short* __restrict__ feat,
             const int* __restrict__ cnt, const int2* __restrict__ bucket,
             int2* __restrict__ gbuf, const float* __restrict__ eattr,
             float* __restrict__ eagg8,
             const short8* __restrict__ bhi, const short8* __restrict__ blo,
             const float* __restrict__ WeDp, const float* __restrict__ biasDp,
             void* __restrict__ outp, int N)
{
    int tid = threadIdx.x, lane = tid & 63;
    int gw = (blockIdx.x * 256 + tid) >> 6;
    int A = gw * 2;
    if (A >= N) return;
    bool hasB = (A + 1 < N);
    int sel = lane >> 5, slot = lane & 31;
    int cl = lane & 15, tq = lane >> 4;

    // ---- paired edge metadata + e8 ----
    int srcl = 0; float nmv = 0.f;
    float e8A[CE_], e8B[CE_];
    if constexpr (L0) {
        int nmy = min(A + sel, N - 1);
        int degf = cnt[nmy];
        int degn = min(degf, MAXD);
        bool valid = (slot < degn) && (A + sel < N);
        int2 me = bucket[(size_t)A * MAXD + lane];     // rows A, A+1 contiguous
        srcl = valid ? me.x : 0;
        int eidl = valid ? me.y : 0;
        if (valid) nmv = rsqrtf((float)max(cnt[srcl], 1) * (float)max(degf, 1));
        gbuf[(size_t)A * MAXD + lane] = make_int2(srcl, __float_as_int(nmv));
        const float4* ep = (const float4*)(eattr + (size_t)eidl * CE_);
        float4 q0 = ep[0], q1 = ep[1];
        float a8[8] = { nmv*q0.x, nmv*q0.y, nmv*q0.z, nmv*q0.w,
                        nmv*q1.x, nmv*q1.y, nmv*q1.z, nmv*q1.w };
#pragma unroll
        for (int o = 16; o; o >>= 1) {
#pragma unroll
            for (int j = 0; j < 8; j++) a8[j] += __shfl_xor(a8[j], o, 64);
        }
#pragma unroll
        for (int j = 0; j < 8; j++) { e8A[j] = rlf(a8[j], 0); e8B[j] = rlf(a8[j], 32); }
        if (slot == 0 && (A + sel < N)) {
            float4* eo = (float4*)(eagg8 + (size_t)(A + sel) * CE_);
            eo[0] = make_float4(a8[0], a8[1], a8[2], a8[3]);
            eo[1] = make_float4(a8[4], a8[5], a8[6], a8[7]);
        }
    } else {
        int2 gv = gbuf[(size_t)A * MAXD + lane];       // both nodes, one read
        srcl = gv.x; nmv = __int_as_float(gv.y);
        const float4* eA = (const float4*)(eagg8 + (size_t)A * CE_);
        float4 r0 = eA[0], r1 = eA[1];
        e8A[0]=r0.x; e8A[1]=r0.y; e8A[2]=r0.z; e8A[3]=r0.w;
        e8A[4]=r1.x; e8A[5]=r1.y; e8A[6]=r1.z; e8A[7]=r1.w;
        int Bn = hasB ? A + 1 : A;
        const float4* eB = (const float4*)(eagg8 + (size_t)Bn * CE_);
        float4 s0 = eB[0], s1 = eB[1];
        e8B[0]=s0.x; e8B[1]=s0.y; e8B[2]=s0.z; e8B[3]=s0.w;
        e8B[4]=s1.x; e8B[5]=s1.y; e8B[6]=s1.z; e8B[7]=s1.w;
    }
    unsigned long long bal = __ballot(nmv != 0.f);
    int degA = __popcll(bal & 0xffffffffull);
    int degB = __popcll(bal >> 32);
    int mx = max(degA, degB);

    // ---- constants once per pair: B-fragments + base (bias + e8 @ We) ----
    short8 bh[4], bl_[4];
#pragma unroll
    for (int b = 0; b < 4; b++) { bh[b] = bhi[b * 64 + lane]; bl_[b] = blo[b * 64 + lane]; }
    float baseA[4], baseB[4];
#pragma unroll
    for (int b = 0; b < 4; b++) {
        float bs = biasDp[b * 64 + lane];
        const float* wd = WeDp + (size_t)(b * 64 + lane) * 8;
        float sA = bs, sB = bs;
#pragma unroll
        for (int j = 0; j < CE_; j++) {
            float w = wd[j];
            sA = fmaf(e8A[j], w, sA);
            sB = fmaf(e8B[j], w, sB);
        }
        baseA[b] = sA; baseB[b] = sB;
    }

    // ---- interleaved gather: 2 edges per node per iter (8 loads in flight) --
    constexpr int ROWS = L0 ? (T_ * CIN_) : (T_ * HID_);   // 192 | 384 shorts
    int myoff = L0 ? ((cl < 12 ? cl * CIN_ : 0) + tq * 8)
                   : ((cl < 12 ? cl * HID_ : 0) + tq * 8);
    bool ldon = L0 ? (lane < 32) : true;
    float aA[8] = {0,0,0,0,0,0,0,0}, aB[8] = {0,0,0,0,0,0,0,0};
    for (int eb = 0; eb < mx; eb += 2) {
        int i0 = eb & 31, i1 = (eb + 1) & 31;
        int   sA0 = rli(srcl, i0),      sA1 = rli(srcl, i1);
        int   sB0 = rli(srcl, 32 + i0), sB1 = rli(srcl, 32 + i1);
        float nA0 = rlf(nmv, i0),       nA1 = rlf(nmv, i1);
        float nB0 = rlf(nmv, 32 + i0),  nB1 = rlf(nmv, 32 + i1);
        uint4 vA0 = make_uint4(0,0,0,0), vA1 = vA0, vB0 = vA0, vB1 = vA0;
        if (ldon && eb < degA) {                     // wave-uniform guard
            vA0 = *(const uint4*)(feat + (size_t)sA0 * ROWS + myoff);
            vA1 = *(const uint4*)(feat + (size_t)sA1 * ROWS + myoff);
        }
        if (ldon && eb < degB) {
            vB0 = *(const uint4*)(feat + (size_t)sB0 * ROWS + myoff);
            vB1 = *(const uint4*)(feat + (size_t)sB1 * ROWS + myoff);
        }
        aA[0] = fmaf(nA0, bflo(vA0.x), aA[0]); aA[1] = fmaf(nA0, bfhi(vA0.x), aA[1]);
        aA[2] = fmaf(nA0, bflo(vA0.y), aA[2]); aA[3] = fmaf(nA0, bfhi(vA0.y), aA[3]);
        aA[4] = fmaf(nA0, bflo(vA0.z), aA[4]); aA[5] = fmaf(nA0, bfhi(vA0.z), aA[5]);
        aA[6] = fmaf(nA0, bflo(vA0.w), aA[6]); aA[7] = fmaf(nA0, bfhi(vA0.w), aA[7]);
        aA[0] = fmaf(nA1, bflo(vA1.x), aA[0]); aA[1] = fmaf(nA1, bfhi(vA1.x), aA[1]);
        aA[2] = fmaf(nA1, bflo(vA1.y), aA[2]); aA[3] = fmaf(nA1, bfhi(vA1.y), aA[3]);
        aA[4] = fmaf(nA1, bflo(vA1.z), aA[4]); aA[5] = fmaf(nA1, bfhi(vA1.z), aA[5]);
        aA[6] = fmaf(nA1, bflo(vA1.w), aA[6]); aA[7] = fmaf(nA1, bfhi(vA1.w), aA[7]);
        aB[0] = fmaf(nB0, bflo(vB0.x), aB[0]); aB[1] = fmaf(nB0, bfhi(vB0.x), aB[1]);
        aB[2] = fmaf(nB0, bflo(vB0.y), aB[2]); aB[3] = fmaf(nB0, bfhi(vB0.y), aB[3]);
        aB[4] = fmaf(nB0, bflo(vB0.z), aB[4]); aB[5] = fmaf(nB0, bfhi(vB0.z), aB[5]);
        aB[6] = fmaf(nB0, bflo(vB0.w), aB[6]); aB[7] = fmaf(nB0, bfhi(vB0.w), aB[7]);
        aB[0] = fmaf(nB1, bflo(vB1.x), aB[0]); aB[1] = fmaf(nB1, bfhi(vB1.x), aB[1]);
        aB[2] = fmaf(nB1, bflo(vB1.y), aB[2]); aB[3] = fmaf(nB1, bfhi(vB1.y), aB[3]);
        aB[4] = fmaf(nB1, bflo(vB1.z), aB[4]); aB[5] = fmaf(nB1, bfhi(vB1.z), aB[5]);
        aB[6] = fmaf(nB1, bflo(vB1.w), aB[6]); aB[7] = fmaf(nB1, bfhi(vB1.w), aB[7]);
    }

    // ---- A-fragments (hi/lo split) + MFMA (B-frags reused for both nodes) --
    short8 ahA, alA, ahB, alB;
#pragma unroll
    for (int j = 0; j < 8; j++) {
        unsigned short hA = f2bf(aA[j]);
        ahA[j] = (short)hA; alA[j] = (short)f2bf(aA[j] - bf2f(hA));
        unsigned short hB = f2bf(aB[j]);
        ahB[j] = (short)hB; alB[j] = (short)f2bf(aB[j] - bf2f(hB));
    }
    f32x4 DA[4], DB[4];
#pragma unroll
    for (int b = 0; b < 4; b++) {
        f32x4 C = { baseA[b], baseA[b], baseA[b], baseA[b] };
        C = __builtin_amdgcn_mfma_f32_16x16x32_bf16(alA, bh[b],  C, 0, 0, 0);
        C = __builtin_amdgcn_mfma_f32_16x16x32_bf16(ahA, bl_[b], C, 0, 0, 0);
        C = __builtin_amdgcn_mfma_f32_16x16x32_bf16(ahA, bh[b],  C, 0, 0, 0);
        DA[b] = C;
        f32x4 G = { baseB[b], baseB[b], baseB[b], baseB[b] };
        G = __builtin_amdgcn_mfma_f32_16x16x32_bf16(alB, bh[b],  G, 0, 0, 0);
        G = __builtin_amdgcn_mfma_f32_16x16x32_bf16(ahB, bl_[b], G, 0, 0, 0);
        G = __builtin_amdgcn_mfma_f32_16x16x32_bf16(ahB, bh[b],  G, 0, 0, 0);
        DB[b] = G;
    }

    // ---- gate + write both nodes: D row = tq*4+j = t (t>=12 discarded) -----
    if (tq < 3) {
#pragma unroll
        for (int j = 0; j < 4; j++) {
            int t = tq * 4 + j;
            float oA0 = gatef(DA[0][j], DA[2][j]);
            float oA1 = gatef(DA[1][j], DA[3][j]);
            float oB0 = gatef(DB[0][j], DB[2][j]);
            float oB1 = gatef(DB[1][j], DB[3][j]);
            if constexpr (L0) {
                oA0 = fmaxf(oA0, 0.f); oA1 = fmaxf(oA1, 0.f);
                unsigned pA = (unsigned)f2bf(oA0) | ((unsigned)f2bf(oA1) << 16);
                *(unsigned*)((unsigned short*)outp + (size_t)A * (T_ * HID_) + t * HID_ + 2 * cl) = pA;
                if (hasB) {
                    oB0 = fmaxf(oB0, 0.f); oB1 = fmaxf(oB1, 0.f);
                    unsigned pB = (unsigned)f2bf(oB0) | ((unsigned)f2bf(oB1) << 16);
                    *(unsigned*)((unsigned short*)outp + (size_t)(A + 1) * (T_ * HID_) + t * HID_ + 2 * cl) = pB;
                }
            } else {
                float* op = (float*)outp;
                op[((size_t)t * N + A) * HID_ + cl] = oA0;
                op[((size_t)t * N + A) * HID_ + 16 + cl] = oA1;
                if (hasB) {
                    op[((size_t)t * N + A + 1) * HID_ + cl] = oB0;
                    op[((size_t)t * N + A + 1) * HID_ + 16 + cl] = oB1;
                }
            }
        }
    }
}

// ---- launch ---------------------------------------------------------------

extern "C" void kernel_launch(void* const* d_in, const int* in_sizes, int n_in,
                              void* d_out, int out_size, void* d_ws, size_t ws_size,
                              hipStream_t stream) {
    const float* x     = (const float*)d_in[0];
    const int*   eidx  = (const int*)d_in[1];
    const float* eattr = (const float*)d_in[2];
    const float* Wg0 = (const float*)d_in[3], *Weg0 = (const float*)d_in[4], *bg0 = (const float*)d_in[5];
    const float* Wu0 = (const float*)d_in[6], *Weu0 = (const float*)d_in[7], *bu0 = (const float*)d_in[8];
    const float* Wg1 = (const float*)d_in[9], *Weg1 = (const float*)d_in[10], *bg1 = (const float*)d_in[11];
    const float* Wu1 = (const float*)d_in[12], *Weu1 = (const float*)d_in[13], *bu1 = (const float*)d_in[14];

    int N = in_sizes[0] / (T_ * CIN_);
    int E = in_sizes[1] / 2;
    const int* src = eidx;
    const int* dst = eidx + E;

    char* ws = (char*)d_ws;
    size_t off = 0;
    auto alloc = [&](size_t bytes) -> void* {
        off = (off + 255) & ~(size_t)255;
        void* p = ws + off;
        off += bytes;
        return p;
    };
    int*            cnt    = (int*)alloc((size_t)N * 4);
    int2*           bucket = (int2*)alloc((size_t)(N + 2) * MAXD * 8);
    int2*           gbuf   = (int2*)alloc((size_t)(N + 2) * MAXD * 8);
    float*          eagg8  = (float*)alloc((size_t)N * CE_ * 4);
    unsigned short* Xt     = (unsigned short*)alloc((size_t)N * T_ * CIN_ * 2 + 1024);
    unsigned short* h      = (unsigned short*)alloc((size_t)N * T_ * HID_ * 2 + 1024);
    short8*         BHi    = (short8*)alloc(2 * 4 * 64 * 16);
    short8*         BLo    = (short8*)alloc(2 * 4 * 64 * 16);
    float*          WeD    = (float*)alloc(2 * 4 * 64 * 8 * 4);
    float*          biasD  = (float*)alloc(2 * 4 * 64 * 4);
    (void)ws_size; (void)n_in; (void)out_size;

    k_txp<<<(N * T_ * 4 + 255) / 256, 256, 0, stream>>>(x, Xt, cnt, N,
                                                        Wg0, Wu0, bg0, bu0, Weg0, Weu0,
                                                        Wg1, Wu1, bg1, bu1, Weg1, Weu1,
                                                        BHi, BLo, WeD, biasD);
    k_build<<<(E + 255) / 256, 256, 0, stream>>>(src, dst, E, cnt, bucket);

    int pairs = (N + 1) / 2;
    int blocks = (pairs + 3) / 4;
    k_layer<1><<<blocks, 256, 0, stream>>>(Xt, cnt, bucket, gbuf, eattr, eagg8,
                                           BHi, BLo, WeD, biasD, h, N);
    k_layer<0><<<blocks, 256, 0, stream>>>(h, cnt, bucket, gbuf, eattr, eagg8,
                                           BHi + 256, BLo + 256, WeD + 256 * 8, biasD + 256,
                                           (float*)d_out, N);
}